// Round 4
// baseline (655.946 us; speedup 1.0000x reference)
//
#include <hip/hip_runtime.h>

typedef __attribute__((ext_vector_type(8))) __bf16 bf16x8;
typedef __attribute__((ext_vector_type(4))) float f32x4;
typedef unsigned short u16;
typedef unsigned int u32;
typedef unsigned long long u64;

static constexpr int NROW = 16384;   // b*h*w = 16*32*32
static constexpr int NCODE = 8192;
static constexpr int ZN = 4194304;   // b*c*h*w

#define DELTA_MARGIN 1.5e-4f

// workspace layout (bytes)
static constexpr size_t OFF_ZFLAT = 0;          // fp32 [NROW][256]   16 MB
static constexpr size_t OFF_ZB    = 16777216;   // bf16 [NROW][256]    8 MB
static constexpr size_t OFF_EB    = 25165824;   // bf16 [NCODE][256]   4 MB
static constexpr size_t OFF_CNT   = 29360128;   // int  [NROW]
static constexpr size_t OFF_CAND  = 29425664;   // u16  [NROW][32]
static constexpr size_t OFF_WIDX  = 30474240;   // int  [NROW]
static constexpr size_t OFF_LOSS  = 30539776;   // float

__device__ __forceinline__ u32 encf(float f) {   // monotonic float->uint
  u32 u = __float_as_uint(f);
  return (u & 0x80000000u) ? ~u : (u | 0x80000000u);
}
__device__ __forceinline__ float decf(u32 e) {
  u32 u = (e & 0x80000000u) ? (e ^ 0x80000000u) : ~e;
  return __uint_as_float(u);
}
__device__ __forceinline__ u64 shfl_xor_u64(u64 x, int m) {
  int lo = (int)(x & 0xffffffffull), hi = (int)(x >> 32);
  lo = __shfl_xor(lo, m);
  hi = __shfl_xor(hi, m);
  return ((u64)(u32)hi << 32) | (u32)lo;
}

// ---- numpy fp32 replicas (no FMA contraction allowed!) ----
#pragma clang fp contract(off)

// np.einsum c_einsum float32 sum_of_products_outstride0_two, baseline SSE npyv:
// vstep=4 lanes, 4x-unrolled blocks of 16 with REVERSED muladd chain
// (v += a3*b3, then a2*b2, a1*b1, a0*b0), mul+add separately rounded (no FMA),
// then SSE3 hadd tree (s0+s1)+(s2+s3).  D = RNE(A - 2C); +B is always absorbed.
__device__ float np_dist(const float* __restrict__ zr, const float* __restrict__ er,
                         float A) {
  float s0 = 0.f, s1 = 0.f, s2 = 0.f, s3 = 0.f;
#pragma unroll 4
  for (int i = 0; i < 256; i += 16) {
    s0 = __fadd_rn(__fmul_rn(zr[i + 0], er[i + 0]),
         __fadd_rn(__fmul_rn(zr[i + 4], er[i + 4]),
         __fadd_rn(__fmul_rn(zr[i + 8], er[i + 8]),
         __fadd_rn(__fmul_rn(zr[i + 12], er[i + 12]), s0))));
    s1 = __fadd_rn(__fmul_rn(zr[i + 1], er[i + 1]),
         __fadd_rn(__fmul_rn(zr[i + 5], er[i + 5]),
         __fadd_rn(__fmul_rn(zr[i + 9], er[i + 9]),
         __fadd_rn(__fmul_rn(zr[i + 13], er[i + 13]), s1))));
    s2 = __fadd_rn(__fmul_rn(zr[i + 2], er[i + 2]),
         __fadd_rn(__fmul_rn(zr[i + 6], er[i + 6]),
         __fadd_rn(__fmul_rn(zr[i + 10], er[i + 10]),
         __fadd_rn(__fmul_rn(zr[i + 14], er[i + 14]), s2))));
    s3 = __fadd_rn(__fmul_rn(zr[i + 3], er[i + 3]),
         __fadd_rn(__fmul_rn(zr[i + 7], er[i + 7]),
         __fadd_rn(__fmul_rn(zr[i + 11], er[i + 11]),
         __fadd_rn(__fmul_rn(zr[i + 15], er[i + 15]), s3))));
  }
  float C = __fadd_rn(__fadd_rn(s0, s1), __fadd_rn(s2, s3));
  return __fadd_rn(A, -(2.0f * C));   // 2*C exact; RNE subtract onto ulp(A) grid
}
#pragma clang fp contract(fast)

// ---- kernel 1: z [16,256,32,32] -> z_flat [16384,256] fp32 + bf16 (LDS transpose) ----
__global__ __launch_bounds__(256) void prep_z_kernel(const float* __restrict__ z,
                                                     float* __restrict__ z_flat,
                                                     __bf16* __restrict__ zb) {
  __shared__ float t[256][33];
  const int bh = blockIdx.x;
  const int b = bh >> 5, h = bh & 31;
  const int w = threadIdx.x & 31, cc = threadIdx.x >> 5;
  const float* src = z + (size_t)b * 262144 + h * 32 + w;   // + c*1024
#pragma unroll
  for (int c0 = 0; c0 < 256; c0 += 8) {
    int c = c0 + cc;
    t[c][w] = src[(size_t)c * 1024];
  }
  __syncthreads();
  const int c = threadIdx.x;
  const int n_base = (b * 32 + h) * 32;
#pragma unroll 4
  for (int w2 = 0; w2 < 32; ++w2) {
    float v = t[c][w2];
    int n = n_base + w2;
    z_flat[(size_t)n * 256 + c] = v;
    zb[(size_t)n * 256 + c] = (__bf16)v;
  }
}

// ---- kernel 2: embedding fp32 -> bf16 ----
__global__ __launch_bounds__(256) void prep_e_kernel(const float* __restrict__ e,
                                                     __bf16* __restrict__ eb) {
  int i = blockIdx.x * 256 + threadIdx.x;   // float4 index; total 524288
  float4 v = ((const float4*)e)[i];
  typedef __attribute__((ext_vector_type(4))) __bf16 bf16x4;
  bf16x4 o;
  o.x = (__bf16)v.x; o.y = (__bf16)v.y; o.z = (__bf16)v.z; o.w = (__bf16)v.w;
  ((bf16x4*)eb)[i] = o;
}

// ---- kernel 3: bf16 MFMA score GEMM + running-max + candidate collection ----
__global__ __launch_bounds__(512, 2) void scores_kernel(const __bf16* __restrict__ zb,
                                                        const __bf16* __restrict__ eb,
                                                        int* __restrict__ g_cnt,
                                                        u16* __restrict__ g_cand) {
  __shared__ u16 Blds[64 * 264];          // 64 codes x 256 k, row stride 528 B
  __shared__ int s_cnt[64];
  __shared__ u32 s_rm[64];
  __shared__ u32 s_cand32[64 * 32 / 2];
  u16* s_cand = (u16*)s_cand32;

  const int tid = threadIdx.x;
  const int row0 = blockIdx.x * 64;
  if (tid < 64) { s_cnt[tid] = 0; s_rm[tid] = 0u; }

  const int wave = tid >> 6, lane = tid & 63;
  const int rg = wave >> 2;      // row group 0..1 (32 rows each)
  const int cg = wave & 3;       // col tile 0..3 (16 codes each)
  const int l15 = lane & 15, l4 = lane >> 4;

  bf16x8 a[2][8];
#pragma unroll
  for (int rt = 0; rt < 2; ++rt) {
    const uint4* abase = (const uint4*)(zb + (size_t)(row0 + rg * 32 + rt * 16 + l15) * 256);
#pragma unroll
    for (int kk = 0; kk < 8; ++kk)
      a[rt][kk] = __builtin_bit_cast(bf16x8, abase[kk * 4 + l4]);
  }

  __syncthreads();

  for (int ch = 0; ch < 128; ++ch) {
    const int k0 = ch * 64;
    const uint4* src = (const uint4*)(eb + (size_t)k0 * 256);
#pragma unroll
    for (int j = 0; j < 4; ++j) {
      int i = j * 512 + tid;
      int r = i >> 5, c16 = i & 31;
      *(uint4*)((char*)Blds + r * 528 + c16 * 16) = src[i];
    }
    __syncthreads();

    f32x4 acc[2] = {{0.f, 0.f, 0.f, 0.f}, {0.f, 0.f, 0.f, 0.f}};
    const char* bbase = (const char*)Blds + (cg * 16 + l15) * 528 + l4 * 16;
#pragma unroll
    for (int kk = 0; kk < 8; ++kk) {
      bf16x8 bf = *(const bf16x8*)(bbase + kk * 64);
      acc[0] = __builtin_amdgcn_mfma_f32_16x16x32_bf16(a[0][kk], bf, acc[0], 0, 0, 0);
      acc[1] = __builtin_amdgcn_mfma_f32_16x16x32_bf16(a[1][kk], bf, acc[1], 0, 0, 0);
    }

#pragma unroll
    for (int rt = 0; rt < 2; ++rt) {
#pragma unroll
      for (int r = 0; r < 4; ++r) {
        float v = acc[rt][r];
        float m = v;
#pragma unroll
        for (int s = 1; s < 16; s <<= 1)
          m = fmaxf(m, __shfl_xor(m, s));
        const int rowl = rg * 32 + rt * 16 + l4 * 4 + r;
        const u32 em = encf(m);
        if (l15 == 0) atomicMax(&s_rm[rowl], em);
        u32 cur = s_rm[rowl];
        if (cur < em) cur = em;
        const float thr = decf(cur) - DELTA_MARGIN;
        if (v > thr) {
          int p = atomicAdd(&s_cnt[rowl], 1);
          if (p < 32) s_cand[rowl * 32 + p] = (u16)(k0 + cg * 16 + l15);
        }
      }
    }
    __syncthreads();
  }

  if (tid < 64) g_cnt[row0 + tid] = s_cnt[tid];
  u32* cd = (u32*)(g_cand + (size_t)row0 * 32);
  cd[tid] = s_cand32[tid];
  cd[tid + 512] = s_cand32[tid + 512];
}

// ---- kernel 4: numpy-fp32-replica rescore; writes widx, idx (fp32), loss ----
__global__ __launch_bounds__(256) void rescore_np_kernel(const float* __restrict__ z_flat,
                                                         const float* __restrict__ emb,
                                                         const int* __restrict__ g_cnt,
                                                         const u16* __restrict__ g_cand,
                                                         int* __restrict__ widx,
                                                         float* __restrict__ loss_ws,
                                                         float* __restrict__ out_idx) {
  __shared__ float zrow_s[4][256];
  __shared__ float red_s[4][16];
  __shared__ u64 key_s[4][32];
  const int wave = threadIdx.x >> 6, lane = threadIdx.x & 63;
  const int n = blockIdx.x * 4 + wave;
  float* zrow = zrow_s[wave];
  {
    float4 v = ((const float4*)(z_flat + (size_t)n * 256))[lane];
    zrow[lane * 4 + 0] = v.x; zrow[lane * 4 + 1] = v.y;
    zrow[lane * 4 + 2] = v.z; zrow[lane * 4 + 3] = v.w;
  }
  // A = np pairwise sum of z^2: halves of 128, 8 sequential accumulators each
  float A;
  {
#pragma clang fp contract(off)
    if (lane < 16) {
      const int half = lane >> 3, j = lane & 7;
      const float* p = zrow + half * 128 + j;
      float r = __fmul_rn(p[0], p[0]);
      for (int i = 8; i < 128; i += 8) {
        float q = __fmul_rn(p[i], p[i]);
        r = __fadd_rn(r, q);
      }
      red_s[wave][lane] = r;
    }
    const float* rr = red_s[wave];   // wave-synchronous LDS (single instr stream)
    float h0 = __fadd_rn(__fadd_rn(__fadd_rn(rr[0], rr[1]), __fadd_rn(rr[2], rr[3])),
                         __fadd_rn(__fadd_rn(rr[4], rr[5]), __fadd_rn(rr[6], rr[7])));
    float h1 = __fadd_rn(__fadd_rn(__fadd_rn(rr[8], rr[9]), __fadd_rn(rr[10], rr[11])),
                         __fadd_rn(__fadd_rn(rr[12], rr[13]), __fadd_rn(rr[14], rr[15])));
    A = __fadd_rn(h0, h1);
  }

  const int cnt = g_cnt[n];
  u64 bestkey = ~0ull;
  if (cnt > 0 && cnt <= 32) {
    if (lane < cnt) {
      const int idx = (int)g_cand[(size_t)n * 32 + lane];
      float D = np_dist(zrow, emb + (size_t)idx * 256, A);
      key_s[wave][lane] = ((u64)__float_as_uint(D) << 16) | (u32)idx;  // D>0: bits monotone
    }
    if (lane == 0) {
      bestkey = key_s[wave][0];
      for (int j = 1; j < cnt; ++j) {
        u64 k = key_s[wave][j];
        if (k < bestkey) bestkey = k;
      }
    }
  } else {  // overflow / empty fallback: full replica scan (~never taken)
    for (int idx = lane; idx < NCODE; idx += 64) {
      float D = np_dist(zrow, emb + (size_t)idx * 256, A);
      u64 k = ((u64)__float_as_uint(D) << 16) | (u32)idx;
      if (k < bestkey) bestkey = k;
    }
#pragma unroll
    for (int m = 32; m >= 1; m >>= 1) {
      u64 o = shfl_xor_u64(bestkey, m);
      if (o < bestkey) bestkey = o;
    }
  }
  if (lane == 0) {
    int bidx = (int)(bestkey & 0xFFFF);
    float D = __uint_as_float((u32)(bestkey >> 16));
    widx[n] = bidx;
    out_idx[n] = (float)bidx;
    atomicAdd(loss_ws, D);   // Sum(z-e)^2 ~ D (+B ~6e-7, negligible vs thr)
  }
}

// ---- kernel 5: z_st[b,c,h,w] = emb[idx[b,h,w]][c] + loss finalize ----
__global__ __launch_bounds__(256) void finalize_kernel(const float* __restrict__ emb,
                                                       const int* __restrict__ widx,
                                                       float* __restrict__ z_st,
                                                       const float* __restrict__ loss_ws,
                                                       float* __restrict__ out_loss) {
  __shared__ float t[32][257];
  __shared__ int idxs[32];
  const int bh = blockIdx.x;
  const int b = bh >> 5, h = bh & 31;
  const int n0 = (b * 32 + h) * 32;
  if (threadIdx.x < 32) idxs[threadIdx.x] = widx[n0 + threadIdx.x];
  __syncthreads();
  for (int wi = 0; wi < 32; ++wi)
    t[wi][threadIdx.x] = emb[(size_t)idxs[wi] * 256 + threadIdx.x];  // coalesced 1KB
  __syncthreads();
  const int w = threadIdx.x & 31, c0 = threadIdx.x >> 5;
  float* dst = z_st + (size_t)b * 262144 + h * 32 + w;               // + c*1024
#pragma unroll
  for (int cj = 0; cj < 32; ++cj) {
    int c = c0 + cj * 8;
    dst[(size_t)c * 1024] = t[w][c];
  }
  if (bh == 0 && threadIdx.x == 0)
    *out_loss = loss_ws[0] * (1.25f / 4194304.0f);
}

extern "C" void kernel_launch(void* const* d_in, const int* in_sizes, int n_in,
                              void* d_out, int out_size, void* d_ws, size_t ws_size,
                              hipStream_t stream) {
  const float* z = (const float*)d_in[0];     // fp32 [16,256,32,32]
  const float* emb = (const float*)d_in[1];   // fp32 [8192,256]
  char* ws = (char*)d_ws;
  float* z_flat = (float*)(ws + OFF_ZFLAT);
  __bf16* zb = (__bf16*)(ws + OFF_ZB);
  __bf16* eb = (__bf16*)(ws + OFF_EB);
  int* g_cnt = (int*)(ws + OFF_CNT);
  u16* g_cand = (u16*)(ws + OFF_CAND);
  int* widx = (int*)(ws + OFF_WIDX);
  float* loss_ws = (float*)(ws + OFF_LOSS);
  float* out = (float*)d_out;
  float* out_loss = out + ZN;       // output 1
  float* out_idx = out + ZN + 1;    // output 2 (indices as fp32 ints)

  (void)hipMemsetAsync(loss_ws, 0, sizeof(float), stream);
  prep_z_kernel<<<512, 256, 0, stream>>>(z, z_flat, zb);
  prep_e_kernel<<<2048, 256, 0, stream>>>(emb, eb);
  scores_kernel<<<256, 512, 0, stream>>>(zb, eb, g_cnt, g_cand);
  rescore_np_kernel<<<4096, 256, 0, stream>>>(z_flat, emb, g_cnt, g_cand, widx, loss_ws, out_idx);
  finalize_kernel<<<512, 256, 0, stream>>>(emb, widx, out, loss_ws, out_loss);
}

// Round 5
// 555.862 us; speedup vs baseline: 1.1801x; 1.1801x over previous
//
#include <hip/hip_runtime.h>

typedef __attribute__((ext_vector_type(8))) __bf16 bf16x8;
typedef __attribute__((ext_vector_type(4))) float f32x4;
typedef unsigned short u16;
typedef unsigned int u32;
typedef unsigned long long u64;

static constexpr int NROW = 16384;   // b*h*w = 16*32*32
static constexpr int NCODE = 8192;
static constexpr int ZN = 4194304;   // b*c*h*w

#define DELTA_MARGIN 1.5e-4f

// workspace layout (bytes) — same 30.5 MB footprint that passed in round 4
static constexpr size_t OFF_ZFLAT = 0;          // fp32 [NROW][256]   16 MB
static constexpr size_t OFF_ZB    = 16777216;   // bf16 [NROW][256]    8 MB
static constexpr size_t OFF_EB    = 25165824;   // bf16 [NCODE][256]   4 MB
static constexpr size_t OFF_CNT   = 29360128;   // int  [NROW]        64 KB
static constexpr size_t OFF_CAND  = 29425664;   // u16  [NROW][32]     1 MB
static constexpr size_t OFF_WIDX  = 30474240;   // int  [NROW]        64 KB
static constexpr size_t OFF_LOSS  = 30539776;   // float

__device__ __forceinline__ u32 encf(float f) {   // monotonic float->uint
  u32 u = __float_as_uint(f);
  return (u & 0x80000000u) ? ~u : (u | 0x80000000u);
}
__device__ __forceinline__ float decf(u32 e) {
  u32 u = (e & 0x80000000u) ? (e ^ 0x80000000u) : ~e;
  return __uint_as_float(u);
}
__device__ __forceinline__ u64 shfl_xor_u64(u64 x, int m) {
  int lo = (int)(x & 0xffffffffull), hi = (int)(x >> 32);
  lo = __shfl_xor(lo, m);
  hi = __shfl_xor(hi, m);
  return ((u64)(u32)hi << 32) | (u32)lo;
}

// ---- numpy fp32 replicas (no FMA contraction allowed!) — verified round 4 ----
#pragma clang fp contract(off)
__device__ float np_dist(const float* __restrict__ zr, const float* __restrict__ er,
                         float A) {
  float s0 = 0.f, s1 = 0.f, s2 = 0.f, s3 = 0.f;
#pragma unroll 4
  for (int i = 0; i < 256; i += 16) {
    s0 = __fadd_rn(__fmul_rn(zr[i + 0], er[i + 0]),
         __fadd_rn(__fmul_rn(zr[i + 4], er[i + 4]),
         __fadd_rn(__fmul_rn(zr[i + 8], er[i + 8]),
         __fadd_rn(__fmul_rn(zr[i + 12], er[i + 12]), s0))));
    s1 = __fadd_rn(__fmul_rn(zr[i + 1], er[i + 1]),
         __fadd_rn(__fmul_rn(zr[i + 5], er[i + 5]),
         __fadd_rn(__fmul_rn(zr[i + 9], er[i + 9]),
         __fadd_rn(__fmul_rn(zr[i + 13], er[i + 13]), s1))));
    s2 = __fadd_rn(__fmul_rn(zr[i + 2], er[i + 2]),
         __fadd_rn(__fmul_rn(zr[i + 6], er[i + 6]),
         __fadd_rn(__fmul_rn(zr[i + 10], er[i + 10]),
         __fadd_rn(__fmul_rn(zr[i + 14], er[i + 14]), s2))));
    s3 = __fadd_rn(__fmul_rn(zr[i + 3], er[i + 3]),
         __fadd_rn(__fmul_rn(zr[i + 7], er[i + 7]),
         __fadd_rn(__fmul_rn(zr[i + 11], er[i + 11]),
         __fadd_rn(__fmul_rn(zr[i + 15], er[i + 15]), s3))));
  }
  float C = __fadd_rn(__fadd_rn(s0, s1), __fadd_rn(s2, s3));
  return __fadd_rn(A, -(2.0f * C));
}
#pragma clang fp contract(fast)

// ---- kernel 1: z [16,256,32,32] -> z_flat [16384,256] fp32 + bf16 ----
__global__ __launch_bounds__(256) void prep_z_kernel(const float* __restrict__ z,
                                                     float* __restrict__ z_flat,
                                                     __bf16* __restrict__ zb) {
  __shared__ float t[256][33];
  const int bh = blockIdx.x;
  const int b = bh >> 5, h = bh & 31;
  const int w = threadIdx.x & 31, cc = threadIdx.x >> 5;
  const float* src = z + (size_t)b * 262144 + h * 32 + w;
#pragma unroll
  for (int c0 = 0; c0 < 256; c0 += 8) {
    int c = c0 + cc;
    t[c][w] = src[(size_t)c * 1024];
  }
  __syncthreads();
  const int c = threadIdx.x;
  const int n_base = (b * 32 + h) * 32;
#pragma unroll 4
  for (int w2 = 0; w2 < 32; ++w2) {
    float v = t[c][w2];
    int n = n_base + w2;
    z_flat[(size_t)n * 256 + c] = v;
    zb[(size_t)n * 256 + c] = (__bf16)v;
  }
}

// ---- kernel 2: embedding fp32 -> bf16 ----
__global__ __launch_bounds__(256) void prep_e_kernel(const float* __restrict__ e,
                                                     __bf16* __restrict__ eb) {
  int i = blockIdx.x * 256 + threadIdx.x;
  float4 v = ((const float4*)e)[i];
  typedef __attribute__((ext_vector_type(4))) __bf16 bf16x4;
  bf16x4 o;
  o.x = (__bf16)v.x; o.y = (__bf16)v.y; o.z = (__bf16)v.z; o.w = (__bf16)v.w;
  ((bf16x4*)eb)[i] = o;
}

// ---- kernel 3: barrier-free two-pass MFMA scores + candidate collection ----
// grid 512 = 256 row-groups x 2 code-halves; 256 threads (4 waves).
// Wave tile: 64 rows x 16 codes; A persistent in regs; B from L2, no LDS.
__global__ __launch_bounds__(256, 2) void scores_kernel(const __bf16* __restrict__ zb,
                                                        const __bf16* __restrict__ eb,
                                                        int* __restrict__ g_cnt,
                                                        u16* __restrict__ g_cand) {
  __shared__ u32 s_rm[64];
  const int tid = threadIdx.x;
  const int wave = tid >> 6, lane = tid & 63;
  const int l15 = lane & 15, l4 = lane >> 4;
  const int row0 = (blockIdx.x >> 1) * 64;
  const int code0 = (blockIdx.x & 1) * 4096;
  if (tid < 64) s_rm[tid] = 0u;
  __syncthreads();

  // persistent A fragments: 4 row-tiles x 8 k-steps (layout verified round 4)
  bf16x8 a[4][8];
#pragma unroll
  for (int t = 0; t < 4; ++t) {
    const uint4* ab = (const uint4*)(zb + (size_t)(row0 + t * 16 + l15) * 256);
#pragma unroll
    for (int kk = 0; kk < 8; ++kk)
      a[t][kk] = __builtin_bit_cast(bf16x8, ab[kk * 4 + l4]);
  }

  float mx[4][4];
#pragma unroll
  for (int t = 0; t < 4; ++t)
#pragma unroll
    for (int r = 0; r < 4; ++r) mx[t][r] = -1e30f;

  // ---- pass 1: per-lane running max, zero cross-lane work in the loop ----
  for (int ch = 0; ch < 64; ++ch) {
    const int cb = code0 + ch * 64 + wave * 16;
    const uint4* bb = (const uint4*)(eb + (size_t)(cb + l15) * 256);
    f32x4 acc[4] = {{0.f,0.f,0.f,0.f},{0.f,0.f,0.f,0.f},{0.f,0.f,0.f,0.f},{0.f,0.f,0.f,0.f}};
#pragma unroll
    for (int kk = 0; kk < 8; ++kk) {
      bf16x8 bf = __builtin_bit_cast(bf16x8, bb[kk * 4 + l4]);
      acc[0] = __builtin_amdgcn_mfma_f32_16x16x32_bf16(a[0][kk], bf, acc[0], 0, 0, 0);
      acc[1] = __builtin_amdgcn_mfma_f32_16x16x32_bf16(a[1][kk], bf, acc[1], 0, 0, 0);
      acc[2] = __builtin_amdgcn_mfma_f32_16x16x32_bf16(a[2][kk], bf, acc[2], 0, 0, 0);
      acc[3] = __builtin_amdgcn_mfma_f32_16x16x32_bf16(a[3][kk], bf, acc[3], 0, 0, 0);
    }
#pragma unroll
    for (int t = 0; t < 4; ++t)
#pragma unroll
      for (int r = 0; r < 4; ++r) mx[t][r] = fmaxf(mx[t][r], acc[t][r]);
  }

  // one-time reduce: 16-lane col max per element, then cross-wave via LDS
#pragma unroll
  for (int t = 0; t < 4; ++t)
#pragma unroll
    for (int r = 0; r < 4; ++r) {
      float m = mx[t][r];
#pragma unroll
      for (int s = 1; s < 16; s <<= 1) m = fmaxf(m, __shfl_xor(m, s));
      mx[t][r] = m;
    }
  if (l15 == 0) {
#pragma unroll
    for (int t = 0; t < 4; ++t)
#pragma unroll
      for (int r = 0; r < 4; ++r)
        atomicMax(&s_rm[t * 16 + l4 * 4 + r], encf(mx[t][r]));
  }
  __syncthreads();
  float thr[4][4];
#pragma unroll
  for (int t = 0; t < 4; ++t)
#pragma unroll
    for (int r = 0; r < 4; ++r)
      thr[t][r] = decf(s_rm[t * 16 + l4 * 4 + r]) - DELTA_MARGIN;

  // ---- pass 2: identical MFMA chain (bit-identical), collect vs final thr ----
  for (int ch = 0; ch < 64; ++ch) {
    const int cb = code0 + ch * 64 + wave * 16;
    const uint4* bb = (const uint4*)(eb + (size_t)(cb + l15) * 256);
    f32x4 acc[4] = {{0.f,0.f,0.f,0.f},{0.f,0.f,0.f,0.f},{0.f,0.f,0.f,0.f},{0.f,0.f,0.f,0.f}};
#pragma unroll
    for (int kk = 0; kk < 8; ++kk) {
      bf16x8 bf = __builtin_bit_cast(bf16x8, bb[kk * 4 + l4]);
      acc[0] = __builtin_amdgcn_mfma_f32_16x16x32_bf16(a[0][kk], bf, acc[0], 0, 0, 0);
      acc[1] = __builtin_amdgcn_mfma_f32_16x16x32_bf16(a[1][kk], bf, acc[1], 0, 0, 0);
      acc[2] = __builtin_amdgcn_mfma_f32_16x16x32_bf16(a[2][kk], bf, acc[2], 0, 0, 0);
      acc[3] = __builtin_amdgcn_mfma_f32_16x16x32_bf16(a[3][kk], bf, acc[3], 0, 0, 0);
    }
#pragma unroll
    for (int t = 0; t < 4; ++t)
#pragma unroll
      for (int r = 0; r < 4; ++r) {
        if (acc[t][r] > thr[t][r]) {
          const int rowg = row0 + t * 16 + l4 * 4 + r;
          int p = atomicAdd(&g_cnt[rowg], 1);
          if (p < 32) g_cand[(size_t)rowg * 32 + p] = (u16)(cb + l15);
        }
      }
  }
}

// ---- kernel 4: numpy-fp32-replica rescore (verified) over merged candidates ----
__global__ __launch_bounds__(256) void rescore_np_kernel(const float* __restrict__ z_flat,
                                                         const float* __restrict__ emb,
                                                         const int* __restrict__ g_cnt,
                                                         const u16* __restrict__ g_cand,
                                                         int* __restrict__ widx,
                                                         float* __restrict__ loss_ws,
                                                         float* __restrict__ out_idx) {
  __shared__ float zrow_s[4][256];
  __shared__ float red_s[4][16];
  const int wave = threadIdx.x >> 6, lane = threadIdx.x & 63;
  const int n = blockIdx.x * 4 + wave;
  float* zrow = zrow_s[wave];
  {
    float4 v = ((const float4*)(z_flat + (size_t)n * 256))[lane];
    zrow[lane * 4 + 0] = v.x; zrow[lane * 4 + 1] = v.y;
    zrow[lane * 4 + 2] = v.z; zrow[lane * 4 + 3] = v.w;
  }
  float A;
  {
#pragma clang fp contract(off)
    if (lane < 16) {
      const int half = lane >> 3, j = lane & 7;
      const float* p = zrow + half * 128 + j;
      float r = __fmul_rn(p[0], p[0]);
      for (int i = 8; i < 128; i += 8) {
        float q = __fmul_rn(p[i], p[i]);
        r = __fadd_rn(r, q);
      }
      red_s[wave][lane] = r;
    }
    const float* rr = red_s[wave];
    float h0 = __fadd_rn(__fadd_rn(__fadd_rn(rr[0], rr[1]), __fadd_rn(rr[2], rr[3])),
                         __fadd_rn(__fadd_rn(rr[4], rr[5]), __fadd_rn(rr[6], rr[7])));
    float h1 = __fadd_rn(__fadd_rn(__fadd_rn(rr[8], rr[9]), __fadd_rn(rr[10], rr[11])),
                         __fadd_rn(__fadd_rn(rr[12], rr[13]), __fadd_rn(rr[14], rr[15])));
    A = __fadd_rn(h0, h1);
  }

  const int cnt = g_cnt[n];
  u64 bestkey = ~0ull;
  if (cnt >= 1 && cnt <= 32) {
    for (int j = lane; j < cnt; j += 64) {
      const int idx = (int)g_cand[(size_t)n * 32 + j];
      float D = np_dist(zrow, emb + (size_t)idx * 256, A);
      u64 k = ((u64)__float_as_uint(D) << 16) | (u32)idx;
      if (k < bestkey) bestkey = k;
    }
  } else {  // overflow safety net (P ~ 0)
    for (int idx = lane; idx < NCODE; idx += 64) {
      float D = np_dist(zrow, emb + (size_t)idx * 256, A);
      u64 k = ((u64)__float_as_uint(D) << 16) | (u32)idx;
      if (k < bestkey) bestkey = k;
    }
  }
#pragma unroll
  for (int m = 32; m >= 1; m >>= 1) {
    u64 o = shfl_xor_u64(bestkey, m);
    if (o < bestkey) bestkey = o;
  }
  if (lane == 0) {
    int bidx = (int)(bestkey & 0xFFFF);
    float D = __uint_as_float((u32)(bestkey >> 16));
    widx[n] = bidx;
    out_idx[n] = (float)bidx;
    atomicAdd(loss_ws, D);
  }
}

// ---- kernel 5: z_st[b,c,h,w] = emb[idx[b,h,w]][c] + loss finalize ----
__global__ __launch_bounds__(256) void finalize_kernel(const float* __restrict__ emb,
                                                       const int* __restrict__ widx,
                                                       float* __restrict__ z_st,
                                                       const float* __restrict__ loss_ws,
                                                       float* __restrict__ out_loss) {
  __shared__ float t[32][257];
  __shared__ int idxs[32];
  const int bh = blockIdx.x;
  const int b = bh >> 5, h = bh & 31;
  const int n0 = (b * 32 + h) * 32;
  if (threadIdx.x < 32) idxs[threadIdx.x] = widx[n0 + threadIdx.x];
  __syncthreads();
  for (int wi = 0; wi < 32; ++wi)
    t[wi][threadIdx.x] = emb[(size_t)idxs[wi] * 256 + threadIdx.x];
  __syncthreads();
  const int w = threadIdx.x & 31, c0 = threadIdx.x >> 5;
  float* dst = z_st + (size_t)b * 262144 + h * 32 + w;
#pragma unroll
  for (int cj = 0; cj < 32; ++cj) {
    int c = c0 + cj * 8;
    dst[(size_t)c * 1024] = t[w][c];
  }
  if (bh == 0 && threadIdx.x == 0)
    *out_loss = loss_ws[0] * (1.25f / 4194304.0f);
}

extern "C" void kernel_launch(void* const* d_in, const int* in_sizes, int n_in,
                              void* d_out, int out_size, void* d_ws, size_t ws_size,
                              hipStream_t stream) {
  const float* z = (const float*)d_in[0];
  const float* emb = (const float*)d_in[1];
  char* ws = (char*)d_ws;
  float* z_flat = (float*)(ws + OFF_ZFLAT);
  __bf16* zb = (__bf16*)(ws + OFF_ZB);
  __bf16* eb = (__bf16*)(ws + OFF_EB);
  int* g_cnt = (int*)(ws + OFF_CNT);
  u16* g_cand = (u16*)(ws + OFF_CAND);
  int* widx = (int*)(ws + OFF_WIDX);
  float* loss_ws = (float*)(ws + OFF_LOSS);
  float* out = (float*)d_out;
  float* out_loss = out + ZN;
  float* out_idx = out + ZN + 1;

  (void)hipMemsetAsync(g_cnt, 0, NROW * sizeof(int), stream);
  (void)hipMemsetAsync(loss_ws, 0, sizeof(float), stream);
  prep_z_kernel<<<512, 256, 0, stream>>>(z, z_flat, zb);
  prep_e_kernel<<<2048, 256, 0, stream>>>(emb, eb);
  scores_kernel<<<512, 256, 0, stream>>>(zb, eb, g_cnt, g_cand);
  rescore_np_kernel<<<4096, 256, 0, stream>>>(z_flat, emb, g_cnt, g_cand, widx, loss_ws, out_idx);
  finalize_kernel<<<512, 256, 0, stream>>>(emb, widx, out, loss_ws, out_loss);
}

// Round 6
// 393.003 us; speedup vs baseline: 1.6691x; 1.4144x over previous
//
#include <hip/hip_runtime.h>

typedef __attribute__((ext_vector_type(8))) __bf16 bf16x8;
typedef __attribute__((ext_vector_type(4))) float f32x4;
typedef unsigned short u16;
typedef unsigned int u32;
typedef unsigned long long u64;

static constexpr int NROW = 16384;   // b*h*w
static constexpr int NCODE = 8192;
static constexpr int ZN = 4194304;   // b*c*h*w
static constexpr int CAND_CAP = 64;

#define DELTA_MARGIN 1.5e-4f

// workspace layout (bytes) — 14.1 MB total
static constexpr size_t OFF_ZB   = 0;          // bf16 permuted z fragments  8 MB
static constexpr size_t OFF_EB   = 8388608;    // bf16 permuted e fragments  4 MB
static constexpr size_t OFF_CNT  = 12582912;   // int  [NROW]
static constexpr size_t OFF_CAND = 12648448;   // u16  [NROW][64]  2 MB
static constexpr size_t OFF_LOSS = 14745600;   // float
static constexpr size_t OFF_CTR  = 14745604;   // int

__device__ __forceinline__ u32 encf(float f) {
  u32 u = __float_as_uint(f);
  return (u & 0x80000000u) ? ~u : (u | 0x80000000u);
}
__device__ __forceinline__ float decf(u32 e) {
  u32 u = (e & 0x80000000u) ? (e ^ 0x80000000u) : ~e;
  return __uint_as_float(u);
}
__device__ __forceinline__ u64 shfl_xor_u64(u64 x, int m) {
  int lo = (int)(x & 0xffffffffull), hi = (int)(x >> 32);
  lo = __shfl_xor(lo, m);
  hi = __shfl_xor(hi, m);
  return ((u64)(u32)hi << 32) | (u32)lo;
}

// ---- numpy fp32 replica (verified round 4/5; no FMA contraction) ----
#pragma clang fp contract(off)
__device__ float np_dist(const float* __restrict__ zr, const float* __restrict__ er,
                         float A) {
  float s0 = 0.f, s1 = 0.f, s2 = 0.f, s3 = 0.f;
#pragma unroll 4
  for (int i = 0; i < 256; i += 16) {
    s0 = __fadd_rn(__fmul_rn(zr[i + 0], er[i + 0]),
         __fadd_rn(__fmul_rn(zr[i + 4], er[i + 4]),
         __fadd_rn(__fmul_rn(zr[i + 8], er[i + 8]),
         __fadd_rn(__fmul_rn(zr[i + 12], er[i + 12]), s0))));
    s1 = __fadd_rn(__fmul_rn(zr[i + 1], er[i + 1]),
         __fadd_rn(__fmul_rn(zr[i + 5], er[i + 5]),
         __fadd_rn(__fmul_rn(zr[i + 9], er[i + 9]),
         __fadd_rn(__fmul_rn(zr[i + 13], er[i + 13]), s1))));
    s2 = __fadd_rn(__fmul_rn(zr[i + 2], er[i + 2]),
         __fadd_rn(__fmul_rn(zr[i + 6], er[i + 6]),
         __fadd_rn(__fmul_rn(zr[i + 10], er[i + 10]),
         __fadd_rn(__fmul_rn(zr[i + 14], er[i + 14]), s2))));
    s3 = __fadd_rn(__fmul_rn(zr[i + 3], er[i + 3]),
         __fadd_rn(__fmul_rn(zr[i + 7], er[i + 7]),
         __fadd_rn(__fmul_rn(zr[i + 11], er[i + 11]),
         __fadd_rn(__fmul_rn(zr[i + 15], er[i + 15]), s3))));
  }
  float C = __fadd_rn(__fadd_rn(s0, s1), __fadd_rn(s2, s3));
  return __fadd_rn(A, -(2.0f * C));
}
#pragma clang fp contract(fast)

// ---- kernel 1: fused prep — z transpose->permuted zb_p, e->permuted eb_p, zero cnt/loss/ctr
// permuted fragment layout (identical for A and B): byte addr =
//   (idx>>4)*8192 + kk*1024 + (idx&15)*64 + l4*16 + j*2   where k = kk*32+l4*8+j
__global__ __launch_bounds__(256) void prep_kernel(const float* __restrict__ z,
                                                   const float* __restrict__ e,
                                                   u16* __restrict__ zb_p,
                                                   u16* __restrict__ eb_p,
                                                   int* __restrict__ g_cnt,
                                                   float* __restrict__ loss_ws,
                                                   int* __restrict__ ctr) {
  const int blk = blockIdx.x;
  if (blk < 512) {
    __shared__ float t[256][33];
    const int b = blk >> 5, h = blk & 31;
    const int w = threadIdx.x & 31, cc = threadIdx.x >> 5;
    const float* src = z + (size_t)b * 262144 + h * 32 + w;
#pragma unroll
    for (int c0 = 0; c0 < 256; c0 += 8) t[c0 + cc][w] = src[(size_t)(c0 + cc) * 1024];
    if (threadIdx.x < 32) g_cnt[blk * 32 + threadIdx.x] = 0;
    if (blk == 0 && threadIdx.x == 0) { *loss_ws = 0.f; *ctr = 0; }
    __syncthreads();
    const int c = threadIdx.x;
    const size_t coff = (size_t)(c >> 5) * 512 + (size_t)((c >> 3) & 3) * 8 + (c & 7);
    const int n_base = blk * 32;
#pragma unroll 4
    for (int w2 = 0; w2 < 32; ++w2) {
      const int n = n_base + w2;
      __bf16 v = (__bf16)t[c][w2];
      zb_p[(size_t)(n >> 4) * 4096 + (size_t)(n & 15) * 32 + coff] = __builtin_bit_cast(u16, v);
    }
  } else {
    const int tile = blk - 512;                    // 0..511 code tiles of 16
    const float* ebase = e + (size_t)tile * 4096;  // 16 codes * 256
    u16* obase = eb_p + (size_t)tile * 4096;
#pragma unroll
    for (int gi = 0; gi < 2; ++gi) {
      const int g = gi * 256 + threadIdx.x;        // granule within tile
      const int kk = g >> 6, l15 = (g >> 2) & 15, l4 = g & 3;
      const float* s = ebase + l15 * 256 + kk * 32 + l4 * 8;
      float4 v0 = ((const float4*)s)[0];
      float4 v1 = ((const float4*)s)[1];
      bf16x8 o;
      o[0] = (__bf16)v0.x; o[1] = (__bf16)v0.y; o[2] = (__bf16)v0.z; o[3] = (__bf16)v0.w;
      o[4] = (__bf16)v1.x; o[5] = (__bf16)v1.y; o[6] = (__bf16)v1.z; o[7] = (__bf16)v1.w;
      *(bf16x8*)(obase + (size_t)g * 8) = o;
    }
  }
}

// ---- kernel 2: single-pass MFMA scores + running-max candidate push ----
// grid 512 = 256 row-groups x 2 code-halves; 512 thr (8 waves = 2 rg x 4 cg).
// A persistent in AGPR (a[2][8]); B: 32KB chunk staged via global_load_lds.
__global__ __launch_bounds__(512, 4) void scores_kernel(const u16* __restrict__ zb_p,
                                                        const u16* __restrict__ eb_p,
                                                        int* __restrict__ g_cnt,
                                                        u16* __restrict__ g_cand) {
  __shared__ u16 Bbuf[16384];   // 32 KB: one 64-code chunk (permuted granules)
  __shared__ u32 s_rm[64];
  const int tid = threadIdx.x;
  const int wave = tid >> 6, lane = tid & 63;
  const int rg = wave >> 2, cg = wave & 3;
  const int l15 = lane & 15, l4 = lane >> 4;
  const int row0 = (int)(blockIdx.x >> 1) * 64;
  const int code0 = (int)(blockIdx.x & 1) * 4096;
  if (tid < 64) s_rm[tid] = 0u;

  bf16x8 a[2][8];
#pragma unroll
  for (int rt = 0; rt < 2; ++rt) {
    const uint4* ab = (const uint4*)(zb_p + (size_t)((row0 >> 4) + rg * 2 + rt) * 4096);
    const int gidx = l15 * 4 + l4;
#pragma unroll
    for (int kk = 0; kk < 8; ++kk)
      a[rt][kk] = __builtin_bit_cast(bf16x8, ab[kk * 64 + gidx]);
  }
  __syncthreads();

  const char* gsrc0 = (const char*)eb_p + (size_t)code0 * 512;
  char* lbase = (char*)Bbuf;

  for (int ch = 0; ch < 64; ++ch) {
    const char* g = gsrc0 + (size_t)ch * 32768;
#pragma unroll
    for (int i = 0; i < 4; ++i) {
      __builtin_amdgcn_global_load_lds(
          (const __attribute__((address_space(1))) void*)(g + i * 8192 + tid * 16),
          (__attribute__((address_space(3))) void*)(lbase + i * 8192 + tid * 16),
          16, 0, 0);
    }
    __syncthreads();   // compiler drains vmcnt before barrier

    f32x4 acc[2] = {{0.f, 0.f, 0.f, 0.f}, {0.f, 0.f, 0.f, 0.f}};
    const bf16x8* bb = (const bf16x8*)Bbuf + cg * 512 + l15 * 4 + l4;
#pragma unroll
    for (int kk = 0; kk < 8; ++kk) {
      bf16x8 bf = bb[kk * 64];
      acc[0] = __builtin_amdgcn_mfma_f32_16x16x32_bf16(a[0][kk], bf, acc[0], 0, 0, 0);
      acc[1] = __builtin_amdgcn_mfma_f32_16x16x32_bf16(a[1][kk], bf, acc[1], 0, 0, 0);
    }

    // epilogue: row-max over the wave's 16 codes, lazy shared running max, push
#pragma unroll
    for (int rt = 0; rt < 2; ++rt)
#pragma unroll
      for (int r = 0; r < 4; ++r) {
        float v = acc[rt][r];
        float m = v;
#pragma unroll
        for (int s = 1; s < 16; s <<= 1) m = fmaxf(m, __shfl_xor(m, s));
        const int rowl = rg * 32 + rt * 16 + l4 * 4 + r;
        u32 cur = s_rm[rowl];
        const u32 em = encf(m);
        if (l15 == 0 && em > cur) atomicMax(&s_rm[rowl], em);
        if (cur < em) cur = em;                 // cur always a real score now
        const float thr = decf(cur) - DELTA_MARGIN;
        if (v > thr) {                          // superset of final-threshold set
          const int rowg = row0 + rowl;
          int p = atomicAdd(&g_cnt[rowg], 1);
          if (p < CAND_CAP)
            g_cand[(size_t)rowg * CAND_CAP + p] = (u16)(code0 + ch * 64 + cg * 16 + l15);
        }
      }
    __syncthreads();   // before overwriting Bbuf
  }
}

// ---- kernel 3: fused numpy-replica rescore + z_st gather/transpose + loss ----
__global__ __launch_bounds__(256) void rescore_fin_kernel(const float* __restrict__ z,
                                                          const float* __restrict__ emb,
                                                          const int* __restrict__ g_cnt,
                                                          const u16* __restrict__ g_cand,
                                                          float* __restrict__ loss_ws,
                                                          int* __restrict__ ctr,
                                                          float* __restrict__ z_st,
                                                          float* __restrict__ out_loss,
                                                          float* __restrict__ out_idx) {
  __shared__ float zrows[32][257];
  __shared__ float red_s[4][16];
  __shared__ int widx_s[32];
  __shared__ float bsum_s[4];
  const int bh = blockIdx.x;
  const int b = bh >> 5, h = bh & 31;
  const int n0 = bh * 32;
  const int wave = threadIdx.x >> 6, lane = threadIdx.x & 63;
  {
    const float* src = z + (size_t)b * 262144 + h * 32;
    const int w = threadIdx.x & 31, c8 = threadIdx.x >> 5;
#pragma unroll
    for (int c0 = 0; c0 < 256; c0 += 8) {
      int c = c0 + c8;
      zrows[w][c] = src[(size_t)c * 1024 + w];
    }
  }
  __syncthreads();

  float wsum = 0.f;
  for (int j = 0; j < 8; ++j) {
    const int r = wave * 8 + j;
    const int n = n0 + r;
    const float* zrow = zrows[r];
    float A;
    {
#pragma clang fp contract(off)
      if (lane < 16) {
        const int half = lane >> 3, jj = lane & 7;
        const float* p = zrow + half * 128 + jj;
        float acc = __fmul_rn(p[0], p[0]);
        for (int i = 8; i < 128; i += 8) acc = __fadd_rn(acc, __fmul_rn(p[i], p[i]));
        red_s[wave][lane] = acc;
      }
      const float* rr = red_s[wave];
      float h0 = __fadd_rn(__fadd_rn(__fadd_rn(rr[0], rr[1]), __fadd_rn(rr[2], rr[3])),
                           __fadd_rn(__fadd_rn(rr[4], rr[5]), __fadd_rn(rr[6], rr[7])));
      float h1 = __fadd_rn(__fadd_rn(__fadd_rn(rr[8], rr[9]), __fadd_rn(rr[10], rr[11])),
                           __fadd_rn(__fadd_rn(rr[12], rr[13]), __fadd_rn(rr[14], rr[15])));
      A = __fadd_rn(h0, h1);
    }
    const int cnt = g_cnt[n];
    u64 bestkey = ~0ull;
    if (cnt >= 1 && cnt <= CAND_CAP) {
      for (int t = lane; t < cnt; t += 64) {
        const int idx = (int)g_cand[(size_t)n * CAND_CAP + t];
        float D = np_dist(zrow, emb + (size_t)idx * 256, A);
        u64 k = ((u64)__float_as_uint(D) << 16) | (u32)idx;
        if (k < bestkey) bestkey = k;
      }
    } else {   // overflow safety net (P ~ 0)
      for (int idx = lane; idx < NCODE; idx += 64) {
        float D = np_dist(zrow, emb + (size_t)idx * 256, A);
        u64 k = ((u64)__float_as_uint(D) << 16) | (u32)idx;
        if (k < bestkey) bestkey = k;
      }
    }
#pragma unroll
    for (int m = 32; m >= 1; m >>= 1) {
      u64 o = shfl_xor_u64(bestkey, m);
      if (o < bestkey) bestkey = o;
    }
    if (lane == 0) {
      const int bidx = (int)(bestkey & 0xFFFF);
      widx_s[r] = bidx;
      out_idx[n] = (float)bidx;
      wsum += __uint_as_float((u32)(bestkey >> 16));
    }
  }
  if (lane == 0) bsum_s[wave] = wsum;
  __syncthreads();

  if (threadIdx.x == 0) {
    float s = bsum_s[0] + bsum_s[1] + bsum_s[2] + bsum_s[3];
    atomicAdd(loss_ws, s);
    __threadfence();
    int t = atomicAdd(ctr, 1);
    if (t == 511)
      *out_loss = atomicAdd(loss_ws, 0.0f) * (1.25f / 4194304.0f);
  }

  // gather chosen codebook rows (reuse zrows) and transpose-store z_st
  for (int wi = 0; wi < 32; ++wi)
    zrows[wi][threadIdx.x] = emb[(size_t)widx_s[wi] * 256 + threadIdx.x];
  __syncthreads();
  const int w = threadIdx.x & 31, c0 = threadIdx.x >> 5;
  float* dst = z_st + (size_t)b * 262144 + h * 32 + w;
#pragma unroll
  for (int cj = 0; cj < 32; ++cj) {
    int c = c0 + cj * 8;
    dst[(size_t)c * 1024] = zrows[w][c];
  }
}

extern "C" void kernel_launch(void* const* d_in, const int* in_sizes, int n_in,
                              void* d_out, int out_size, void* d_ws, size_t ws_size,
                              hipStream_t stream) {
  const float* z = (const float*)d_in[0];     // fp32 [16,256,32,32]
  const float* emb = (const float*)d_in[1];   // fp32 [8192,256]
  char* ws = (char*)d_ws;
  u16* zb_p = (u16*)(ws + OFF_ZB);
  u16* eb_p = (u16*)(ws + OFF_EB);
  int* g_cnt = (int*)(ws + OFF_CNT);
  u16* g_cand = (u16*)(ws + OFF_CAND);
  float* loss_ws = (float*)(ws + OFF_LOSS);
  int* ctr = (int*)(ws + OFF_CTR);
  float* out = (float*)d_out;
  float* out_loss = out + ZN;       // output 1
  float* out_idx = out + ZN + 1;    // output 2

  prep_kernel<<<1024, 256, 0, stream>>>(z, emb, zb_p, eb_p, g_cnt, loss_ws, ctr);
  scores_kernel<<<512, 512, 0, stream>>>(zb_p, eb_p, g_cnt, g_cand);
  rescore_fin_kernel<<<512, 256, 0, stream>>>(z, emb, g_cnt, g_cand, loss_ws, ctr,
                                              out, out_loss, out_idx);
}

// Round 7
// 333.729 us; speedup vs baseline: 1.9655x; 1.1776x over previous
//
#include <hip/hip_runtime.h>

typedef __attribute__((ext_vector_type(8))) __bf16 bf16x8;
typedef __attribute__((ext_vector_type(4))) float f32x4;
typedef unsigned short u16;
typedef unsigned int u32;
typedef unsigned long long u64;

static constexpr int NROW = 16384;   // b*h*w
static constexpr int NCODE = 8192;
static constexpr int ZN = 4194304;   // b*c*h*w
static constexpr int CAND_CAP = 128;

#define DELTA_MARGIN 1.5e-4f

// workspace layout (bytes) — 16.1 MB
static constexpr size_t OFF_ZB   = 0;          // bf16 lane-ordered z granules  8 MB
static constexpr size_t OFF_EB   = 8388608;    // bf16 lane-ordered e granules  4 MB
static constexpr size_t OFF_CNT  = 12582912;   // int  [NROW]
static constexpr size_t OFF_CAND = 12648448;   // u16  [NROW][128]  4 MB
static constexpr size_t OFF_LOSS = 16842752;   // float
static constexpr size_t OFF_CTR  = 16842756;   // int

__device__ __forceinline__ u32 encf(float f) {
  u32 u = __float_as_uint(f);
  return (u & 0x80000000u) ? ~u : (u | 0x80000000u);
}
__device__ __forceinline__ float decf(u32 e) {
  u32 u = (e & 0x80000000u) ? (e ^ 0x80000000u) : ~e;
  return __uint_as_float(u);
}
__device__ __forceinline__ u64 shfl_xor_u64(u64 x, int m) {
  int lo = (int)(x & 0xffffffffull), hi = (int)(x >> 32);
  lo = __shfl_xor(lo, m);
  hi = __shfl_xor(hi, m);
  return ((u64)(u32)hi << 32) | (u32)lo;
}

// ---- numpy fp32 replica (verified rounds 4-6; identical op order, float4 loads) ----
#pragma clang fp contract(off)
__device__ float np_dist(const float* __restrict__ zr, const float* __restrict__ er,
                         float A) {
  const float4* e4 = (const float4*)er;
  float s0 = 0.f, s1 = 0.f, s2 = 0.f, s3 = 0.f;
#pragma unroll 4
  for (int i16 = 0; i16 < 16; ++i16) {
    float4 ea = e4[i16 * 4 + 0], eb = e4[i16 * 4 + 1];
    float4 ec = e4[i16 * 4 + 2], ed = e4[i16 * 4 + 3];
    const float* zz = zr + i16 * 16;
    s0 = __fadd_rn(__fmul_rn(zz[0], ea.x),
         __fadd_rn(__fmul_rn(zz[4], eb.x),
         __fadd_rn(__fmul_rn(zz[8], ec.x),
         __fadd_rn(__fmul_rn(zz[12], ed.x), s0))));
    s1 = __fadd_rn(__fmul_rn(zz[1], ea.y),
         __fadd_rn(__fmul_rn(zz[5], eb.y),
         __fadd_rn(__fmul_rn(zz[9], ec.y),
         __fadd_rn(__fmul_rn(zz[13], ed.y), s1))));
    s2 = __fadd_rn(__fmul_rn(zz[2], ea.z),
         __fadd_rn(__fmul_rn(zz[6], eb.z),
         __fadd_rn(__fmul_rn(zz[10], ec.z),
         __fadd_rn(__fmul_rn(zz[14], ed.z), s2))));
    s3 = __fadd_rn(__fmul_rn(zz[3], ea.w),
         __fadd_rn(__fmul_rn(zz[7], eb.w),
         __fadd_rn(__fmul_rn(zz[11], ec.w),
         __fadd_rn(__fmul_rn(zz[15], ed.w), s3))));
  }
  float C = __fadd_rn(__fadd_rn(s0, s1), __fadd_rn(s2, s3));
  return __fadd_rn(A, -(2.0f * C));
}
#pragma clang fp contract(fast)

// ---- kernel 1: prep — z transpose -> zb_p, e -> eb_p (lane-ordered granules) ----
// granule(tile16, kk, l4, l15) at index tile*512 + kk*64 + l4*16 + l15 (16B each),
// content = X[idx = tile*16 + l15][k = kk*32 + l4*8 + j], j=0..7.
__global__ __launch_bounds__(256) void prep_kernel(const float* __restrict__ z,
                                                   const float* __restrict__ e,
                                                   u16* __restrict__ zb_p,
                                                   u16* __restrict__ eb_p,
                                                   int* __restrict__ g_cnt,
                                                   float* __restrict__ loss_ws,
                                                   int* __restrict__ ctr) {
  const int blk = blockIdx.x;
  if (blk < 512) {
    __shared__ float t[256][33];
    const int b = blk >> 5, h = blk & 31;
    const int w = threadIdx.x & 31, cc = threadIdx.x >> 5;
    const float* src = z + (size_t)b * 262144 + h * 32 + w;
#pragma unroll
    for (int c0 = 0; c0 < 256; c0 += 8) t[c0 + cc][w] = src[(size_t)(c0 + cc) * 1024];
    if (threadIdx.x < 32) g_cnt[blk * 32 + threadIdx.x] = 0;
    if (blk == 0 && threadIdx.x == 0) { *loss_ws = 0.f; *ctr = 0; }
    __syncthreads();
    const int c = threadIdx.x;
    const int kk = c >> 5, l4q = (c >> 3) & 3, j = c & 7;
#pragma unroll 4
    for (int w2 = 0; w2 < 32; ++w2) {
      const int n = blk * 32 + w2;
      __bf16 v = (__bf16)t[c][w2];
      zb_p[(size_t)(n >> 4) * 4096 + kk * 512 + l4q * 128 + (n & 15) * 8 + j] =
          __builtin_bit_cast(u16, v);
    }
  } else {
    const int blk2 = blk - 512;
#pragma unroll
    for (int gi = 0; gi < 2; ++gi) {
      const int G = blk2 * 512 + gi * 256 + threadIdx.x;   // granule id, 0..262143
      const int ch = G >> 11, r = G & 2047;
      const int cg = r >> 9, kk = (r >> 6) & 7, l4 = (r >> 4) & 3, l15 = r & 15;
      const int code = ch * 64 + cg * 16 + l15;
      const float* s = e + (size_t)code * 256 + kk * 32 + l4 * 8;
      float4 v0 = ((const float4*)s)[0];
      float4 v1 = ((const float4*)s)[1];
      bf16x8 o;
      o[0] = (__bf16)v0.x; o[1] = (__bf16)v0.y; o[2] = (__bf16)v0.z; o[3] = (__bf16)v0.w;
      o[4] = (__bf16)v1.x; o[5] = (__bf16)v1.y; o[6] = (__bf16)v1.z; o[7] = (__bf16)v1.w;
      *(bf16x8*)(eb_p + (size_t)G * 8) = o;
    }
  }
}

// ---- kernel 2: single-pass MFMA scores, per-lane thresholds, candidate push ----
// grid 512 = 256 row-groups x 2 code-halves; 512 thr = 8 waves (2 rg x 4 cg).
__global__ __launch_bounds__(512, 4) void scores_kernel(const u16* __restrict__ zb_p,
                                                        const u16* __restrict__ eb_p,
                                                        int* __restrict__ g_cnt,
                                                        u16* __restrict__ g_cand) {
  __shared__ u16 Bbuf[16384];   // 32 KB: one 64-code chunk of lane-ordered granules
  __shared__ u32 s_rm[64];
  const int tid = threadIdx.x;
  const int wave = tid >> 6, lane = tid & 63;
  const int rg = wave >> 2, cg = wave & 3;
  const int l15 = lane & 15, l4 = lane >> 4;
  const int row0 = (int)(blockIdx.x >> 1) * 64;
  const int code0 = (int)(blockIdx.x & 1) * 4096;
  if (tid < 64) s_rm[tid] = encf(-3.0e38f);

  // persistent A fragments (lane-ordered granules -> coalesced 1KB loads)
  bf16x8 a[2][8];
#pragma unroll
  for (int rt = 0; rt < 2; ++rt) {
    const uint4* ab = (const uint4*)(zb_p + (size_t)((row0 >> 4) + rg * 2 + rt) * 4096);
#pragma unroll
    for (int kk = 0; kk < 8; ++kk)
      a[rt][kk] = __builtin_bit_cast(bf16x8, ab[kk * 64 + lane]);
  }
  __syncthreads();

  const char* gsrc0 = (const char*)eb_p + (size_t)code0 * 512;
  char* lbase = (char*)Bbuf;
  const bf16x8* bb = (const bf16x8*)Bbuf + cg * 512 + lane;
  const int rowbase = row0 + rg * 32;

#define STAGE(CH)                                                                  \
  {                                                                                \
    const char* g = gsrc0 + (size_t)(CH) * 32768;                                  \
    _Pragma("unroll")                                                              \
    for (int i = 0; i < 4; ++i)                                                    \
      __builtin_amdgcn_global_load_lds(                                            \
          (const __attribute__((address_space(1))) void*)(g + i * 8192 + tid * 16),\
          (__attribute__((address_space(3))) void*)(lbase + i * 8192 + tid * 16),  \
          16, 0, 0);                                                               \
  }

#define COMPUTE()                                                                  \
  f32x4 acc[2] = {{0.f, 0.f, 0.f, 0.f}, {0.f, 0.f, 0.f, 0.f}};                     \
  _Pragma("unroll")                                                                \
  for (int kk = 0; kk < 8; ++kk) {                                                 \
    bf16x8 bf = bb[kk * 64];                                                       \
    acc[0] = __builtin_amdgcn_mfma_f32_16x16x32_bf16(a[0][kk], bf, acc[0], 0, 0, 0);\
    acc[1] = __builtin_amdgcn_mfma_f32_16x16x32_bf16(a[1][kk], bf, acc[1], 0, 0, 0);\
  }

#define SYNC_THR()                                                                 \
  {                                                                                \
    _Pragma("unroll")                                                              \
    for (int rt = 0; rt < 2; ++rt)                                                 \
      _Pragma("unroll")                                                            \
      for (int r = 0; r < 4; ++r) {                                                \
        float m = lmax[rt][r];                                                     \
        _Pragma("unroll")                                                          \
        for (int s = 1; s < 16; s <<= 1) m = fmaxf(m, __shfl_xor(m, s));           \
        if (l15 == 0) atomicMax(&s_rm[rg * 32 + rt * 16 + l4 * 4 + r], encf(m));   \
      }                                                                            \
    __syncthreads();                                                               \
    _Pragma("unroll")                                                              \
    for (int rt = 0; rt < 2; ++rt)                                                 \
      _Pragma("unroll")                                                            \
      for (int r = 0; r < 4; ++r)                                                  \
        lmax[rt][r] = fmaxf(lmax[rt][r], decf(s_rm[rg * 32 + rt * 16 + l4 * 4 + r]));\
  }

  float lmax[2][4];
  // seed: chunk 0, no pushes, then share thresholds block-wide
  STAGE(0);
  __syncthreads();
  {
    COMPUTE();
#pragma unroll
    for (int rt = 0; rt < 2; ++rt)
#pragma unroll
      for (int r = 0; r < 4; ++r) lmax[rt][r] = acc[rt][r];
  }
  SYNC_THR();

  for (int ch = 0; ch < 64; ++ch) {
    if (ch) {                       // chunk 0 is still resident from the seed
      __syncthreads();
      STAGE(ch);
      __syncthreads();
    }
    COMPUTE();
#pragma unroll
    for (int rt = 0; rt < 2; ++rt)
#pragma unroll
      for (int r = 0; r < 4; ++r) {
        float v = acc[rt][r];
        if (v > lmax[rt][r] - DELTA_MARGIN) {     // superset of final-thr set
          const int rowg = rowbase + rt * 16 + l4 * 4 + r;
          int p = atomicAdd(&g_cnt[rowg], 1);
          if (p < CAND_CAP)
            g_cand[(size_t)rowg * CAND_CAP + p] = (u16)(code0 + ch * 64 + cg * 16 + l15);
        }
        lmax[rt][r] = fmaxf(lmax[rt][r], v);
      }
    if ((ch & 7) == 7 && ch != 63) SYNC_THR();
  }
#undef STAGE
#undef COMPUTE
#undef SYNC_THR
}

// ---- kernel 3: fused numpy-replica rescore + z_st gather/transpose + loss ----
__global__ __launch_bounds__(256) void rescore_fin_kernel(const float* __restrict__ z,
                                                          const float* __restrict__ emb,
                                                          const int* __restrict__ g_cnt,
                                                          const u16* __restrict__ g_cand,
                                                          float* __restrict__ loss_ws,
                                                          int* __restrict__ ctr,
                                                          float* __restrict__ z_st,
                                                          float* __restrict__ out_loss,
                                                          float* __restrict__ out_idx) {
  __shared__ float zrows[32][257];
  __shared__ float red_s[4][16];
  __shared__ int widx_s[32];
  __shared__ float bsum_s[4];
  const int bh = blockIdx.x;
  const int b = bh >> 5, h = bh & 31;
  const int n0 = bh * 32;
  const int wave = threadIdx.x >> 6, lane = threadIdx.x & 63;
  {
    const float* src = z + (size_t)b * 262144 + h * 32;
    const int w = threadIdx.x & 31, c8 = threadIdx.x >> 5;
#pragma unroll
    for (int c0 = 0; c0 < 256; c0 += 8) {
      int c = c0 + c8;
      zrows[w][c] = src[(size_t)c * 1024 + w];
    }
  }
  __syncthreads();

  float wsum = 0.f;
  for (int j = 0; j < 8; ++j) {
    const int r = wave * 8 + j;
    const int n = n0 + r;
    const float* zrow = zrows[r];
    float A;
    {
#pragma clang fp contract(off)
      if (lane < 16) {
        const int half = lane >> 3, jj = lane & 7;
        const float* p = zrow + half * 128 + jj;
        float acc = __fmul_rn(p[0], p[0]);
        for (int i = 8; i < 128; i += 8) acc = __fadd_rn(acc, __fmul_rn(p[i], p[i]));
        red_s[wave][lane] = acc;
      }
      const float* rr = red_s[wave];
      float h0 = __fadd_rn(__fadd_rn(__fadd_rn(rr[0], rr[1]), __fadd_rn(rr[2], rr[3])),
                           __fadd_rn(__fadd_rn(rr[4], rr[5]), __fadd_rn(rr[6], rr[7])));
      float h1 = __fadd_rn(__fadd_rn(__fadd_rn(rr[8], rr[9]), __fadd_rn(rr[10], rr[11])),
                           __fadd_rn(__fadd_rn(rr[12], rr[13]), __fadd_rn(rr[14], rr[15])));
      A = __fadd_rn(h0, h1);
    }
    const int cnt = g_cnt[n];
    u64 bestkey = ~0ull;
    if (cnt >= 1 && cnt <= CAND_CAP) {
      for (int t = lane; t < cnt; t += 64) {
        const int idx = (int)g_cand[(size_t)n * CAND_CAP + t];
        float D = np_dist(zrow, emb + (size_t)idx * 256, A);
        u64 k = ((u64)__float_as_uint(D) << 16) | (u32)idx;
        if (k < bestkey) bestkey = k;
      }
    } else {   // overflow safety net (P ~ 0)
      for (int idx = lane; idx < NCODE; idx += 64) {
        float D = np_dist(zrow, emb + (size_t)idx * 256, A);
        u64 k = ((u64)__float_as_uint(D) << 16) | (u32)idx;
        if (k < bestkey) bestkey = k;
      }
    }
#pragma unroll
    for (int m = 32; m >= 1; m >>= 1) {
      u64 o = shfl_xor_u64(bestkey, m);
      if (o < bestkey) bestkey = o;
    }
    if (lane == 0) {
      const int bidx = (int)(bestkey & 0xFFFF);
      widx_s[r] = bidx;
      out_idx[n] = (float)bidx;
      wsum += __uint_as_float((u32)(bestkey >> 16));
    }
  }
  if (lane == 0) bsum_s[wave] = wsum;
  __syncthreads();

  if (threadIdx.x == 0) {
    float s = bsum_s[0] + bsum_s[1] + bsum_s[2] + bsum_s[3];
    atomicAdd(loss_ws, s);
    __threadfence();
    int t = atomicAdd(ctr, 1);
    if (t == 511)
      *out_loss = atomicAdd(loss_ws, 0.0f) * (1.25f / 4194304.0f);
  }

  for (int wi = 0; wi < 32; ++wi)
    zrows[wi][threadIdx.x] = emb[(size_t)widx_s[wi] * 256 + threadIdx.x];
  __syncthreads();
  const int w = threadIdx.x & 31, c0 = threadIdx.x >> 5;
  float* dst = z_st + (size_t)b * 262144 + h * 32 + w;
#pragma unroll
  for (int cj = 0; cj < 32; ++cj) {
    int c = c0 + cj * 8;
    dst[(size_t)c * 1024] = zrows[w][c];
  }
}

extern "C" void kernel_launch(void* const* d_in, const int* in_sizes, int n_in,
                              void* d_out, int out_size, void* d_ws, size_t ws_size,
                              hipStream_t stream) {
  const float* z = (const float*)d_in[0];     // fp32 [16,256,32,32]
  const float* emb = (const float*)d_in[1];   // fp32 [8192,256]
  char* ws = (char*)d_ws;
  u16* zb_p = (u16*)(ws + OFF_ZB);
  u16* eb_p = (u16*)(ws + OFF_EB);
  int* g_cnt = (int*)(ws + OFF_CNT);
  u16* g_cand = (u16*)(ws + OFF_CAND);
  float* loss_ws = (float*)(ws + OFF_LOSS);
  int* ctr = (int*)(ws + OFF_CTR);
  float* out = (float*)d_out;
  float* out_loss = out + ZN;       // output 1
  float* out_idx = out + ZN + 1;    // output 2

  prep_kernel<<<1024, 256, 0, stream>>>(z, emb, zb_p, eb_p, g_cnt, loss_ws, ctr);
  scores_kernel<<<512, 512, 0, stream>>>(zb_p, eb_p, g_cnt, g_cand);
  rescore_fin_kernel<<<512, 256, 0, stream>>>(z, emb, g_cnt, g_cand, loss_ws, ctr,
                                              out, out_loss, out_idx);
}